// Round 12
// baseline (305.880 us; speedup 1.0000x reference)
//
#include <hip/hip_runtime.h>

#define NG 20000   // NUM_GENES
#define BB 8       // batch
#define FD 128     // feature dim
#define H1 1250    // h-tiles co-launched with count (rest go with fill; total 2500)

typedef unsigned int uint;
typedef unsigned short ushort;
typedef __attribute__((ext_vector_type(8))) short short8v;
typedef __attribute__((ext_vector_type(4))) float float4v;
typedef __attribute__((ext_vector_type(4))) int int4v;
typedef __attribute__((ext_vector_type(2))) float f2v;

// raw buffer load (CK-style binding). aux=0: normal cached load.
__device__ f2v llvm_rbl_v2f32(int4v srsrc, int voffset, int soffset, int aux)
    __asm("llvm.amdgcn.raw.buffer.load.v2f32");

__device__ __forceinline__ int4v make_srsrc(const void* p) {
    int4v r;
    r.x = (int)(uint)(uintptr_t)p;
    r.y = (int)(uint)((uintptr_t)p >> 32);
    r.z = -1;              // bounds check disabled (all gids in range)
    r.w = 0x00020000;      // raw untyped dword access
    return r;
}

// ---------------- bf16 helpers ----------------
__device__ __forceinline__ ushort f2bf(float x) {
    uint u = __float_as_uint(x);
    u += 0x7FFFu + ((u >> 16) & 1u);   // round to nearest even
    return (ushort)(u >> 16);
}
__device__ __forceinline__ float bf_lo(uint u) { return __uint_as_float(u << 16); }
__device__ __forceinline__ float bf_hi(uint u) { return __uint_as_float(u & 0xFFFF0000u); }

// ---------------- shared h-tile body: one (pair, 32-gene) MFMA tile ----------------
__device__ __forceinline__ void h_tile(char* smem, int hb,
                                       const float* __restrict__ gene,
                                       const ushort* __restrict__ w1t,
                                       uint* __restrict__ h2u, int t) {
    ushort* Al = (ushort*)smem;            // [64][128] bf16 swizzled
    ushort* Bl = (ushort*)(smem + 16384);  // [128][128] bf16 swizzled
    float*  Cl = (float*)smem;             // [64][128] fp32 (reuse after MFMA)
    int p  = hb & 3;                       // batch pair
    int g0 = (hb >> 2) * 32;

    // stage A: rows 0..31 = batch 2p genes g0..g0+31; rows 32..63 = batch 2p+1
#pragma unroll
    for (int s = 0; s < 8; s++) {
        int f = t + s * 256;            // float4 index 0..2047
        int r = f >> 5, k0 = (f & 31) * 4;
        int bb = 2 * p + (r >> 5);
        int gg = g0 + (r & 31);
        float4 v = *(const float4*)(gene + ((size_t)bb * NG + gg) * 128 + k0);
        ushort4 u;
        u.x = f2bf(v.x); u.y = f2bf(v.y); u.z = f2bf(v.z); u.w = f2bf(v.w);
        int byte = (r * 256 + k0 * 2) ^ ((r & 7) << 4);
        *(ushort4*)(smem + byte) = u;
    }
    // stage B: 128x128 bf16 copy (16 chunks of 16B per 128-ushort row)
#pragma unroll
    for (int s = 0; s < 8; s++) {
        int f = t + s * 256;
        int j = f >> 4, k0 = (f & 15) * 8;
        uint4 v = *(const uint4*)(w1t + j * 128 + k0);
        int byte = (j * 256 + k0 * 2) ^ ((j & 7) << 4);
        *(uint4*)((char*)Bl + byte) = v;
    }
    __syncthreads();

    int wid = t >> 6, lane = t & 63;
    int r0 = wid * 16;
    int lrow = lane & 15, lhi = lane >> 4;
    float4v acc[8];
#pragma unroll
    for (int nf = 0; nf < 8; nf++) acc[nf] = (float4v)(0.f);

#pragma unroll
    for (int c = 0; c < 4; c++) {
        int ra = r0 + lrow;
        int byteA = (ra * 256 + (c * 32 + lhi * 8) * 2) ^ ((ra & 7) << 4);
        short8v a = *(short8v*)((char*)Al + byteA);
#pragma unroll
        for (int nf = 0; nf < 8; nf++) {
            int jb = nf * 16 + lrow;
            int byteB = (jb * 256 + (c * 32 + lhi * 8) * 2) ^ ((jb & 7) << 4);
            short8v b = *(short8v*)((char*)Bl + byteB);
            acc[nf] = __builtin_amdgcn_mfma_f32_16x16x32_bf16(a, b, acc[nf], 0, 0, 0);
        }
    }
    __syncthreads();   // Al/Bl dead; reuse as Cl

    // C/D: col = lane&15, row = (lane>>4)*4 + q
#pragma unroll
    for (int nf = 0; nf < 8; nf++) {
#pragma unroll
        for (int q = 0; q < 4; q++) {
            Cl[(r0 + lhi * 4 + q) * 128 + nf * 16 + lrow] = acc[nf][q];
        }
    }
    __syncthreads();

    // pack pairs -> coalesced uint stores: h2u[(p*NG + g)*128 + cc] = {lo=2p, hi=2p+1}
#pragma unroll
    for (int s = 0; s < 16; s++) {
        int flat = t + s * 256;           // 0..4095
        int gi = flat >> 7, cc = flat & 127;
        float lo = Cl[gi * 128 + cc];
        float hi = Cl[(32 + gi) * 128 + cc];
        uint u = (uint)f2bf(lo) | ((uint)f2bf(hi) << 16);
        h2u[((size_t)p * NG + g0 + gi) * 128 + cc] = u;
    }
}

// ---------------- setup: zero ideg / s_acc(8 reps) / ticket, transpose W1 -> bf16 ----------------
__global__ void k_setup(int* ideg, float* s_acc, int* ticket,
                        const float* __restrict__ W1, ushort* w1t, int N) {
    int i = blockIdx.x * blockDim.x + threadIdx.x;
    if (i < N) ideg[i] = 0;
    if (i < 8 * BB * FD) s_acc[i] = 0.0f;
    if (i == 0) *ticket = 0;
    if (i < FD * FD) {                      // w1t[j][k] = W1[k][j]
        int j = i >> 7, k = i & 127;
        w1t[i] = f2bf(W1[k * 128 + j]);
    }
}

// ---------------- MERGED: degree count (blocks 0..eb-1) || h-tiles 0..H1-1 ----------------
__global__ __launch_bounds__(256, 3)
void k_counth(const int* __restrict__ dst, int* ideg, int E, int eb,
              const float* __restrict__ gene, const ushort* __restrict__ w1t,
              uint* __restrict__ h2u) {
    __shared__ __align__(16) char smem[49152];
    if ((int)blockIdx.x < eb) {
        int e = blockIdx.x * 256 + threadIdx.x;
        if (e < E) atomicAdd(&ideg[dst[e]], 1);
        return;
    }
    h_tile(smem, blockIdx.x - eb, gene, w1t, h2u, threadIdx.x);
}

// ---------------- single-pass scan: per-node values + block scan + TICKET base +
// ---------------- self entry + zero pads (CSR segment order need not be node order) ----------------
__global__ void k_scan(const int* __restrict__ ideg, float* dinv, float* cval,
                       int* padcnt, int* offs, const int* __restrict__ gid,
                       int* cursor, int2* csr, int* ticket, int N) {
    __shared__ int sd[256];
    __shared__ int sbase;
    int t = threadIdx.x, idx = blockIdx.x * 256 + t;
    int v = 0, d = 0;
    float iv = 0.f;
    if (idx < N) {
        d = ideg[idx] + 1;              // in-edges + self
        float fd = (float)d;
        dinv[idx] = rsqrtf(fd);
        iv = 1.0f / fd;
        cval[idx] = iv;                 // self-loop contribution to c[i]
        v = (d + 7) & ~7;               // padded to mult of 8
        padcnt[idx] = v;
    }
    sd[t] = v; __syncthreads();
    for (int o = 1; o < 256; o <<= 1) {
        int x = (t >= o) ? sd[t - o] : 0;
        __syncthreads();
        sd[t] += x;
        __syncthreads();
    }
    if (t == 255) sbase = atomicAdd(ticket, sd[255]);   // claim segment base
    __syncthreads();
    if (idx < N) {
        int o = sbase + sd[t] - v;
        offs[idx] = o;
        csr[o] = make_int2(gid[idx], __float_as_int(iv));   // self-loop at slot 0
        cursor[idx] = 1;
        for (int z = d; z < v; z++) csr[o + z] = make_int2(0, 0);  // zero pads
    }
}

// ---------------- MERGED: CSR fill (blocks 0..eb-1) || h-tiles H1..2499 ----------------
__global__ __launch_bounds__(256, 3)
void k_fillh(const int* __restrict__ src, const int* __restrict__ dst,
             const int* __restrict__ gid, const float* __restrict__ dinv,
             float* cval, const int* __restrict__ offs, int* cursor,
             int2* csr, int E, int eb,
             const float* __restrict__ gene, const ushort* __restrict__ w1t,
             uint* __restrict__ h2u) {
    __shared__ __align__(16) char smem[49152];
    if ((int)blockIdx.x < eb) {
        int e = blockIdx.x * 256 + threadIdx.x;
        if (e >= E) return;
        int s = src[e], d = dst[e];
        float nrm = dinv[s] * dinv[d];
        atomicAdd(&cval[s], nrm);
        int pos = atomicAdd(&cursor[d], 1);
        csr[offs[d] + pos] = make_int2(gid[s], __float_as_int(nrm));
        return;
    }
    h_tile(smem, (int)blockIdx.x - eb + H1, gene, w1t, h2u, threadIdx.x);
}

// ---------------- fused gather + relu + weighted reduce (pair-interleaved, padded CSR) ----------------
// Frozen: pinned at the per-CU L2-line-rate ceiling (17.2M lines @ ~0.19 lines/cyc/CU ~= 147us;
// invariant across R6 batch-shard, R7 pairing, R8 L1-bypass, R11 balanced split).
__global__ __launch_bounds__(512)
void k_aggp(const uint* __restrict__ hp, const int2* __restrict__ csr,
            const int* __restrict__ offs, const int* __restrict__ padcnt,
            const float* __restrict__ cval, const float* __restrict__ b1,
            float* __restrict__ s_acc, int N, int wpp) {
    int p    = blockIdx.x & 3;
    int wid  = threadIdx.x >> 6, lane = threadIdx.x & 63;
    int w    = __builtin_amdgcn_readfirstlane((blockIdx.x >> 2) * 8 + wid);
    int4v sr = make_srsrc(hp + (size_t)p * NG * 128);    // pair table base
    int voff = lane * 8;                                  // per-lane byte offset
    int l2 = lane * 2;
    float bx = b1[l2], by = b1[l2 + 1];
    float sx0 = 0.f, sx1 = 0.f, sy0 = 0.f, sy1 = 0.f;

    int i0 = (int)((long long)w * N / wpp);               // balanced split
    int i1 = (int)((long long)(w + 1) * N / wpp);
    for (int i = i0; i < i1; ++i) {
        int   e  = offs[i];
        int   pc = padcnt[i];
        float cv = cval[i];
        float ax0 = 0.f, ax1 = 0.f, ay0 = 0.f, ay1 = 0.f;
        for (int q = 0; q < pc; q += 8) {
            int ee = e + q;
            int2 c0 = csr[ee],     c1 = csr[ee + 1], c2 = csr[ee + 2], c3 = csr[ee + 3];
            int2 c4 = csr[ee + 4], c5 = csr[ee + 5], c6 = csr[ee + 6], c7 = csr[ee + 7];
            f2v u0 = llvm_rbl_v2f32(sr, voff, c0.x << 9, 0);
            f2v u1 = llvm_rbl_v2f32(sr, voff, c1.x << 9, 0);
            f2v u2 = llvm_rbl_v2f32(sr, voff, c2.x << 9, 0);
            f2v u3 = llvm_rbl_v2f32(sr, voff, c3.x << 9, 0);
            f2v u4 = llvm_rbl_v2f32(sr, voff, c4.x << 9, 0);
            f2v u5 = llvm_rbl_v2f32(sr, voff, c5.x << 9, 0);
            f2v u6 = llvm_rbl_v2f32(sr, voff, c6.x << 9, 0);
            f2v u7 = llvm_rbl_v2f32(sr, voff, c7.x << 9, 0);
            float n0 = __int_as_float(c0.y), n1 = __int_as_float(c1.y);
            float n2 = __int_as_float(c2.y), n3 = __int_as_float(c3.y);
            float n4 = __int_as_float(c4.y), n5 = __int_as_float(c5.y);
            float n6 = __int_as_float(c6.y), n7 = __int_as_float(c7.y);
            uint a, b;
            a = __float_as_uint(u0.x); b = __float_as_uint(u0.y);
            ax0 = fmaf(n0, bf_lo(a), ax0); ax1 = fmaf(n0, bf_hi(a), ax1);
            ay0 = fmaf(n0, bf_lo(b), ay0); ay1 = fmaf(n0, bf_hi(b), ay1);
            a = __float_as_uint(u1.x); b = __float_as_uint(u1.y);
            ax0 = fmaf(n1, bf_lo(a), ax0); ax1 = fmaf(n1, bf_hi(a), ax1);
            ay0 = fmaf(n1, bf_lo(b), ay0); ay1 = fmaf(n1, bf_hi(b), ay1);
            a = __float_as_uint(u2.x); b = __float_as_uint(u2.y);
            ax0 = fmaf(n2, bf_lo(a), ax0); ax1 = fmaf(n2, bf_hi(a), ax1);
            ay0 = fmaf(n2, bf_lo(b), ay0); ay1 = fmaf(n2, bf_hi(b), ay1);
            a = __float_as_uint(u3.x); b = __float_as_uint(u3.y);
            ax0 = fmaf(n3, bf_lo(a), ax0); ax1 = fmaf(n3, bf_hi(a), ax1);
            ay0 = fmaf(n3, bf_lo(b), ay0); ay1 = fmaf(n3, bf_hi(b), ay1);
            a = __float_as_uint(u4.x); b = __float_as_uint(u4.y);
            ax0 = fmaf(n4, bf_lo(a), ax0); ax1 = fmaf(n4, bf_hi(a), ax1);
            ay0 = fmaf(n4, bf_lo(b), ay0); ay1 = fmaf(n4, bf_hi(b), ay1);
            a = __float_as_uint(u5.x); b = __float_as_uint(u5.y);
            ax0 = fmaf(n5, bf_lo(a), ax0); ax1 = fmaf(n5, bf_hi(a), ax1);
            ay0 = fmaf(n5, bf_lo(b), ay0); ay1 = fmaf(n5, bf_hi(b), ay1);
            a = __float_as_uint(u6.x); b = __float_as_uint(u6.y);
            ax0 = fmaf(n6, bf_lo(a), ax0); ax1 = fmaf(n6, bf_hi(a), ax1);
            ay0 = fmaf(n6, bf_lo(b), ay0); ay1 = fmaf(n6, bf_hi(b), ay1);
            a = __float_as_uint(u7.x); b = __float_as_uint(u7.y);
            ax0 = fmaf(n7, bf_lo(a), ax0); ax1 = fmaf(n7, bf_hi(a), ax1);
            ay0 = fmaf(n7, bf_lo(b), ay0); ay1 = fmaf(n7, bf_hi(b), ay1);
        }
        sx0 += cv * fmaxf(ax0 + bx, 0.f);
        sx1 += cv * fmaxf(ax1 + bx, 0.f);
        sy0 += cv * fmaxf(ay0 + by, 0.f);
        sy1 += cv * fmaxf(ay1 + by, 0.f);
    }

    // block reduce: 8 waves -> 256 sums -> 1 atomic each into 1-of-8 s_acc replicas
    __shared__ float red[8][256];
    red[wid][lane * 4 + 0] = sx0;
    red[wid][lane * 4 + 1] = sx1;
    red[wid][lane * 4 + 2] = sy0;
    red[wid][lane * 4 + 3] = sy1;
    __syncthreads();
    int t = threadIdx.x;
    if (t < 256) {
        float s = 0.f;
#pragma unroll
        for (int wv = 0; wv < 8; wv++) s += red[wv][t];
        int l = t >> 2, c = t & 3;
        int rep = (blockIdx.x >> 2) & 7;
        atomicAdd(&s_acc[rep * 1024 + (2 * p + (c & 1)) * 128 + 2 * l + (c >> 1)], s);
    }
}

// out[b][j] = (s[b] @ W2)[j] / N + b2[j]   (sums the 8 s_acc replicas; tiny 8x128x128)
__global__ void k_final(const float* __restrict__ s_acc, const float* __restrict__ W2,
                        const float* __restrict__ b2, float* __restrict__ out, float invN) {
    __shared__ float ss[1024];
    int t = threadIdx.x;  // 128 threads
    for (int idx = t; idx < 1024; idx += 128) {
        float s = 0.f;
#pragma unroll
        for (int r = 0; r < 8; r++) s += s_acc[r * 1024 + idx];
        ss[idx] = s;
    }
    __syncthreads();
    float acc[8];
#pragma unroll
    for (int b = 0; b < 8; b++) acc[b] = 0.f;
    for (int k = 0; k < 128; k++) {
        float w = W2[k * 128 + t];
#pragma unroll
        for (int b = 0; b < 8; b++) acc[b] += ss[b * 128 + k] * w;
    }
    float bb = b2[t];
#pragma unroll
    for (int b = 0; b < 8; b++) out[b * 128 + t] = acc[b] * invN + bb;
}

// ---------------- launcher ----------------

extern "C" void kernel_launch(void* const* d_in, const int* in_sizes, int n_in,
                              void* d_out, int out_size, void* d_ws, size_t ws_size,
                              hipStream_t stream) {
    const float* gene = (const float*)d_in[0];
    const float* W1   = (const float*)d_in[1];
    const float* b1   = (const float*)d_in[2];
    const float* W2   = (const float*)d_in[3];
    const float* b2   = (const float*)d_in[4];
    const int*   gid  = (const int*)d_in[5];
    const int*   eidx = (const int*)d_in[6];
    int N = in_sizes[5];
    int E = in_sizes[6] / 2;
    const int* src = eidx;
    const int* dst = eidx + E;
    float* out = (float*)d_out;

    char* p = (char*)d_ws;
    auto alloc = [&](size_t bytes) -> char* {
        char* r = p; p += (bytes + 255) & ~(size_t)255; return r;
    };
    size_t csr_cap = (size_t)E + 8 * (size_t)N;          // padded upper bound (entries)
    int*   ideg   = (int*)  alloc((size_t)N * 4);
    float* dinv   = (float*)alloc((size_t)N * 4);
    float* cval   = (float*)alloc((size_t)N * 4);
    int*   padcnt = (int*)  alloc((size_t)N * 4);
    int*   offs   = (int*)  alloc((size_t)N * 4);
    int*   cursor = (int*)  alloc((size_t)N * 4);
    int*   ticket = (int*)  alloc(256);
    int2*  csr    = (int2*) alloc(csr_cap * 8);
    float* s_acc  = (float*)alloc(8 * 1024 * 4);
    uint*  h2     = (uint*) alloc((size_t)NG * BB * FD * 2);   // 41 MB, bf16 [pair][g][f][2]
    ushort* w1t   = (ushort*)alloc(128 * 128 * 2);             // bf16 W1^T [j][k]

    int nb = (N + 255) / 256;   // 196
    int eb = (E + 255) / 256;   // 3125
    int hblk = 4 * (NG / 32);   // 2500 h-tiles total; H1 with count, rest with fill

    const int NBLK = 2048;      // 512 blocks/pair * 8 waves = 4096 waves per pair
    int wpp = (NBLK / 4) * 8;   // waves per pair

    k_setup <<<nb, 256, 0, stream>>>(ideg, s_acc, ticket, W1, w1t, N);
    k_counth<<<eb + H1, 256, 0, stream>>>(dst, ideg, E, eb, gene, w1t, h2);
    k_scan  <<<nb, 256, 0, stream>>>(ideg, dinv, cval, padcnt, offs, gid,
                                     cursor, csr, ticket, N);
    k_fillh <<<eb + (hblk - H1), 256, 0, stream>>>(src, dst, gid, dinv, cval, offs,
                                                   cursor, csr, E, eb, gene, w1t, h2);
    k_aggp  <<<NBLK, 512, 0, stream>>>(h2, csr, offs, padcnt,
                                       cval, b1, s_acc, N, wpp);
    k_final <<<1, 128, 0, stream>>>(s_acc, W2, b2, out, 1.0f / (float)N);
}

// Round 13
// 275.178 us; speedup vs baseline: 1.1116x; 1.1116x over previous
//
#include <hip/hip_runtime.h>

#define NG 20000   // NUM_GENES
#define BB 8       // batch
#define FD 128     // feature dim
#define HA 1000    // h-tiles with count
#define HB 300     // h-tiles with scan
// HC = 2500 - HA - HB with fill

typedef unsigned int uint;
typedef unsigned short ushort;
typedef __attribute__((ext_vector_type(8))) short short8v;
typedef __attribute__((ext_vector_type(4))) float float4v;
typedef __attribute__((ext_vector_type(4))) int int4v;
typedef __attribute__((ext_vector_type(2))) float f2v;

// raw buffer load (CK-style binding). aux=0: normal cached load.
__device__ f2v llvm_rbl_v2f32(int4v srsrc, int voffset, int soffset, int aux)
    __asm("llvm.amdgcn.raw.buffer.load.v2f32");

__device__ __forceinline__ int4v make_srsrc(const void* p) {
    int4v r;
    r.x = (int)(uint)(uintptr_t)p;
    r.y = (int)(uint)((uintptr_t)p >> 32);
    r.z = -1;              // bounds check disabled (all gids in range)
    r.w = 0x00020000;      // raw untyped dword access
    return r;
}

// ---------------- bf16 helpers ----------------
__device__ __forceinline__ ushort f2bf(float x) {
    uint u = __float_as_uint(x);
    u += 0x7FFFu + ((u >> 16) & 1u);   // round to nearest even
    return (ushort)(u >> 16);
}
__device__ __forceinline__ float bf_lo(uint u) { return __uint_as_float(u << 16); }
__device__ __forceinline__ float bf_hi(uint u) { return __uint_as_float(u & 0xFFFF0000u); }

// ---------------- shared h-tile body: one (pair, 32-gene) MFMA tile ----------------
__device__ __forceinline__ void h_tile(char* smem, int hb,
                                       const float* __restrict__ gene,
                                       const ushort* __restrict__ w1t,
                                       uint* __restrict__ h2u, int t) {
    ushort* Al = (ushort*)smem;            // [64][128] bf16 swizzled
    ushort* Bl = (ushort*)(smem + 16384);  // [128][128] bf16 swizzled
    float*  Cl = (float*)smem;             // [64][128] fp32 (reuse after MFMA)
    int p  = hb & 3;                       // batch pair
    int g0 = (hb >> 2) * 32;

    // stage A: rows 0..31 = batch 2p genes g0..g0+31; rows 32..63 = batch 2p+1
#pragma unroll
    for (int s = 0; s < 8; s++) {
        int f = t + s * 256;            // float4 index 0..2047
        int r = f >> 5, k0 = (f & 31) * 4;
        int bb = 2 * p + (r >> 5);
        int gg = g0 + (r & 31);
        float4 v = *(const float4*)(gene + ((size_t)bb * NG + gg) * 128 + k0);
        ushort4 u;
        u.x = f2bf(v.x); u.y = f2bf(v.y); u.z = f2bf(v.z); u.w = f2bf(v.w);
        int byte = (r * 256 + k0 * 2) ^ ((r & 7) << 4);
        *(ushort4*)(smem + byte) = u;
    }
    // stage B: 128x128 bf16 copy (16 chunks of 16B per 128-ushort row)
#pragma unroll
    for (int s = 0; s < 8; s++) {
        int f = t + s * 256;
        int j = f >> 4, k0 = (f & 15) * 8;
        uint4 v = *(const uint4*)(w1t + j * 128 + k0);
        int byte = (j * 256 + k0 * 2) ^ ((j & 7) << 4);
        *(uint4*)((char*)Bl + byte) = v;
    }
    __syncthreads();

    int wid = t >> 6, lane = t & 63;
    int r0 = wid * 16;
    int lrow = lane & 15, lhi = lane >> 4;
    float4v acc[8];
#pragma unroll
    for (int nf = 0; nf < 8; nf++) acc[nf] = (float4v)(0.f);

#pragma unroll
    for (int c = 0; c < 4; c++) {
        int ra = r0 + lrow;
        int byteA = (ra * 256 + (c * 32 + lhi * 8) * 2) ^ ((ra & 7) << 4);
        short8v a = *(short8v*)((char*)Al + byteA);
#pragma unroll
        for (int nf = 0; nf < 8; nf++) {
            int jb = nf * 16 + lrow;
            int byteB = (jb * 256 + (c * 32 + lhi * 8) * 2) ^ ((jb & 7) << 4);
            short8v b = *(short8v*)((char*)Bl + byteB);
            acc[nf] = __builtin_amdgcn_mfma_f32_16x16x32_bf16(a, b, acc[nf], 0, 0, 0);
        }
    }
    __syncthreads();   // Al/Bl dead; reuse as Cl

    // C/D: col = lane&15, row = (lane>>4)*4 + q
#pragma unroll
    for (int nf = 0; nf < 8; nf++) {
#pragma unroll
        for (int q = 0; q < 4; q++) {
            Cl[(r0 + lhi * 4 + q) * 128 + nf * 16 + lrow] = acc[nf][q];
        }
    }
    __syncthreads();

    // pack pairs -> coalesced uint stores: h2u[(p*NG + g)*128 + cc] = {lo=2p, hi=2p+1}
#pragma unroll
    for (int s = 0; s < 16; s++) {
        int flat = t + s * 256;           // 0..4095
        int gi = flat >> 7, cc = flat & 127;
        float lo = Cl[gi * 128 + cc];
        float hi = Cl[(32 + gi) * 128 + cc];
        uint u = (uint)f2bf(lo) | ((uint)f2bf(hi) << 16);
        h2u[((size_t)p * NG + g0 + gi) * 128 + cc] = u;
    }
}

// ---------------- setup: zero ideg / s_acc(8 reps) / ticket, transpose W1 -> bf16 ----------------
__global__ void k_setup(int* ideg, float* s_acc, int* ticket,
                        const float* __restrict__ W1, ushort* w1t, int N) {
    int i = blockIdx.x * blockDim.x + threadIdx.x;
    if (i < N) ideg[i] = 0;
    if (i < 8 * BB * FD) s_acc[i] = 0.0f;
    if (i == 0) *ticket = 0;
    if (i < FD * FD) {                      // w1t[j][k] = W1[k][j]
        int j = i >> 7, k = i & 127;
        w1t[i] = f2bf(W1[k * 128 + j]);
    }
}

// ---------------- MERGED: degree count + slot record (blocks 0..eb-1) || h-tiles [0,HA) ----------------
__global__ __launch_bounds__(256, 3)
void k_counth(const int* __restrict__ dst, int* ideg, int* epos, int E, int eb,
              const float* __restrict__ gene, const ushort* __restrict__ w1t,
              uint* __restrict__ h2u) {
    __shared__ __align__(16) char smem[49152];
    if ((int)blockIdx.x < eb) {
        int e = blockIdx.x * 256 + threadIdx.x;
        if (e < E) epos[e] = atomicAdd(&ideg[dst[e]], 1);  // count AND record slot
        return;
    }
    h_tile(smem, blockIdx.x - eb, gene, w1t, h2u, threadIdx.x);
}

// ---------------- MERGED: single-pass scan (ticket base) + self + pads || h-tiles [HA,HA+HB) ----------------
__global__ __launch_bounds__(256, 3)
void k_scanh(const int* __restrict__ ideg, float* dinv, float* cval,
             int* padcnt, int* offs, const int* __restrict__ gid,
             int2* csr, int* ticket, int N, int nb,
             const float* __restrict__ gene, const ushort* __restrict__ w1t,
             uint* __restrict__ h2u) {
    __shared__ __align__(16) char smem[49152];
    if ((int)blockIdx.x >= nb) {
        h_tile(smem, (int)blockIdx.x - nb + HA, gene, w1t, h2u, threadIdx.x);
        return;
    }
    int* sd = (int*)smem;
    __shared__ int sbase;
    int t = threadIdx.x, idx = blockIdx.x * 256 + t;
    int v = 0, d = 0;
    float iv = 0.f;
    if (idx < N) {
        d = ideg[idx] + 1;              // in-edges + self
        float fd = (float)d;
        dinv[idx] = rsqrtf(fd);
        iv = 1.0f / fd;
        cval[idx] = iv;                 // self-loop contribution to c[i]
        v = (d + 7) & ~7;               // padded to mult of 8
        padcnt[idx] = v;
    }
    sd[t] = v; __syncthreads();
    for (int o = 1; o < 256; o <<= 1) {
        int x = (t >= o) ? sd[t - o] : 0;
        __syncthreads();
        sd[t] += x;
        __syncthreads();
    }
    if (t == 255) sbase = atomicAdd(ticket, sd[255]);   // claim segment base
    __syncthreads();
    if (idx < N) {
        int o = sbase + sd[t] - v;
        offs[idx] = o;
        csr[o] = make_int2(gid[idx], __float_as_int(iv));   // self-loop at slot 0
        for (int z = d; z < v; z++) csr[o + z] = make_int2(0, 0);  // zero pads
    }
}

// ---------------- MERGED: CSR fill, cursor-free via epos (blocks 0..eb-1) || h-tiles [HA+HB,2500) ----------------
__global__ __launch_bounds__(256, 3)
void k_fillh(const int* __restrict__ src, const int* __restrict__ dst,
             const int* __restrict__ gid, const float* __restrict__ dinv,
             float* cval, const int* __restrict__ offs,
             const int* __restrict__ epos,
             int2* csr, int E, int eb,
             const float* __restrict__ gene, const ushort* __restrict__ w1t,
             uint* __restrict__ h2u) {
    __shared__ __align__(16) char smem[49152];
    if ((int)blockIdx.x < eb) {
        int e = blockIdx.x * 256 + threadIdx.x;
        if (e >= E) return;
        int s = src[e], d = dst[e];
        float nrm = dinv[s] * dinv[d];
        atomicAdd(&cval[s], nrm);
        csr[offs[d] + 1 + epos[e]] = make_int2(gid[s], __float_as_int(nrm));
        return;
    }
    h_tile(smem, (int)blockIdx.x - eb + HA + HB, gene, w1t, h2u, threadIdx.x);
}

// ---------------- fused gather + relu + weighted reduce (pair-interleaved, padded CSR) ----------------
// Frozen: pinned at the per-CU L2-line-rate ceiling (17.2M lines @ ~0.19 lines/cyc/CU ~= 147us;
// invariant across R6 batch-shard, R7 pairing, R8 L1-bypass, R11 balanced split).
__global__ __launch_bounds__(512)
void k_aggp(const uint* __restrict__ hp, const int2* __restrict__ csr,
            const int* __restrict__ offs, const int* __restrict__ padcnt,
            const float* __restrict__ cval, const float* __restrict__ b1,
            float* __restrict__ s_acc, int N, int wpp) {
    int p    = blockIdx.x & 3;
    int wid  = threadIdx.x >> 6, lane = threadIdx.x & 63;
    int w    = __builtin_amdgcn_readfirstlane((blockIdx.x >> 2) * 8 + wid);
    int4v sr = make_srsrc(hp + (size_t)p * NG * 128);    // pair table base
    int voff = lane * 8;                                  // per-lane byte offset
    int l2 = lane * 2;
    float bx = b1[l2], by = b1[l2 + 1];
    float sx0 = 0.f, sx1 = 0.f, sy0 = 0.f, sy1 = 0.f;

    int i0 = (int)((long long)w * N / wpp);               // balanced split
    int i1 = (int)((long long)(w + 1) * N / wpp);
    for (int i = i0; i < i1; ++i) {
        int   e  = offs[i];
        int   pc = padcnt[i];
        float cv = cval[i];
        float ax0 = 0.f, ax1 = 0.f, ay0 = 0.f, ay1 = 0.f;
        for (int q = 0; q < pc; q += 8) {
            int ee = e + q;
            int2 c0 = csr[ee],     c1 = csr[ee + 1], c2 = csr[ee + 2], c3 = csr[ee + 3];
            int2 c4 = csr[ee + 4], c5 = csr[ee + 5], c6 = csr[ee + 6], c7 = csr[ee + 7];
            f2v u0 = llvm_rbl_v2f32(sr, voff, c0.x << 9, 0);
            f2v u1 = llvm_rbl_v2f32(sr, voff, c1.x << 9, 0);
            f2v u2 = llvm_rbl_v2f32(sr, voff, c2.x << 9, 0);
            f2v u3 = llvm_rbl_v2f32(sr, voff, c3.x << 9, 0);
            f2v u4 = llvm_rbl_v2f32(sr, voff, c4.x << 9, 0);
            f2v u5 = llvm_rbl_v2f32(sr, voff, c5.x << 9, 0);
            f2v u6 = llvm_rbl_v2f32(sr, voff, c6.x << 9, 0);
            f2v u7 = llvm_rbl_v2f32(sr, voff, c7.x << 9, 0);
            float n0 = __int_as_float(c0.y), n1 = __int_as_float(c1.y);
            float n2 = __int_as_float(c2.y), n3 = __int_as_float(c3.y);
            float n4 = __int_as_float(c4.y), n5 = __int_as_float(c5.y);
            float n6 = __int_as_float(c6.y), n7 = __int_as_float(c7.y);
            uint a, b;
            a = __float_as_uint(u0.x); b = __float_as_uint(u0.y);
            ax0 = fmaf(n0, bf_lo(a), ax0); ax1 = fmaf(n0, bf_hi(a), ax1);
            ay0 = fmaf(n0, bf_lo(b), ay0); ay1 = fmaf(n0, bf_hi(b), ay1);
            a = __float_as_uint(u1.x); b = __float_as_uint(u1.y);
            ax0 = fmaf(n1, bf_lo(a), ax0); ax1 = fmaf(n1, bf_hi(a), ax1);
            ay0 = fmaf(n1, bf_lo(b), ay0); ay1 = fmaf(n1, bf_hi(b), ay1);
            a = __float_as_uint(u2.x); b = __float_as_uint(u2.y);
            ax0 = fmaf(n2, bf_lo(a), ax0); ax1 = fmaf(n2, bf_hi(a), ax1);
            ay0 = fmaf(n2, bf_lo(b), ay0); ay1 = fmaf(n2, bf_hi(b), ay1);
            a = __float_as_uint(u3.x); b = __float_as_uint(u3.y);
            ax0 = fmaf(n3, bf_lo(a), ax0); ax1 = fmaf(n3, bf_hi(a), ax1);
            ay0 = fmaf(n3, bf_lo(b), ay0); ay1 = fmaf(n3, bf_hi(b), ay1);
            a = __float_as_uint(u4.x); b = __float_as_uint(u4.y);
            ax0 = fmaf(n4, bf_lo(a), ax0); ax1 = fmaf(n4, bf_hi(a), ax1);
            ay0 = fmaf(n4, bf_lo(b), ay0); ay1 = fmaf(n4, bf_hi(b), ay1);
            a = __float_as_uint(u5.x); b = __float_as_uint(u5.y);
            ax0 = fmaf(n5, bf_lo(a), ax0); ax1 = fmaf(n5, bf_hi(a), ax1);
            ay0 = fmaf(n5, bf_lo(b), ay0); ay1 = fmaf(n5, bf_hi(b), ay1);
            a = __float_as_uint(u6.x); b = __float_as_uint(u6.y);
            ax0 = fmaf(n6, bf_lo(a), ax0); ax1 = fmaf(n6, bf_hi(a), ax1);
            ay0 = fmaf(n6, bf_lo(b), ay0); ay1 = fmaf(n6, bf_hi(b), ay1);
            a = __float_as_uint(u7.x); b = __float_as_uint(u7.y);
            ax0 = fmaf(n7, bf_lo(a), ax0); ax1 = fmaf(n7, bf_hi(a), ax1);
            ay0 = fmaf(n7, bf_lo(b), ay0); ay1 = fmaf(n7, bf_hi(b), ay1);
        }
        sx0 += cv * fmaxf(ax0 + bx, 0.f);
        sx1 += cv * fmaxf(ax1 + bx, 0.f);
        sy0 += cv * fmaxf(ay0 + by, 0.f);
        sy1 += cv * fmaxf(ay1 + by, 0.f);
    }

    // block reduce: 8 waves -> 256 sums -> 1 atomic each into 1-of-8 s_acc replicas
    __shared__ float red[8][256];
    red[wid][lane * 4 + 0] = sx0;
    red[wid][lane * 4 + 1] = sx1;
    red[wid][lane * 4 + 2] = sy0;
    red[wid][lane * 4 + 3] = sy1;
    __syncthreads();
    int t = threadIdx.x;
    if (t < 256) {
        float s = 0.f;
#pragma unroll
        for (int wv = 0; wv < 8; wv++) s += red[wv][t];
        int l = t >> 2, c = t & 3;
        int rep = (blockIdx.x >> 2) & 7;
        atomicAdd(&s_acc[rep * 1024 + (2 * p + (c & 1)) * 128 + 2 * l + (c >> 1)], s);
    }
}

// out[b][j] = (s[b] @ W2)[j] / N + b2[j]   (sums the 8 s_acc replicas; tiny 8x128x128)
__global__ void k_final(const float* __restrict__ s_acc, const float* __restrict__ W2,
                        const float* __restrict__ b2, float* __restrict__ out, float invN) {
    __shared__ float ss[1024];
    int t = threadIdx.x;  // 128 threads
    for (int idx = t; idx < 1024; idx += 128) {
        float s = 0.f;
#pragma unroll
        for (int r = 0; r < 8; r++) s += s_acc[r * 1024 + idx];
        ss[idx] = s;
    }
    __syncthreads();
    float acc[8];
#pragma unroll
    for (int b = 0; b < 8; b++) acc[b] = 0.f;
    for (int k = 0; k < 128; k++) {
        float w = W2[k * 128 + t];
#pragma unroll
        for (int b = 0; b < 8; b++) acc[b] += ss[b * 128 + k] * w;
    }
    float bb = b2[t];
#pragma unroll
    for (int b = 0; b < 8; b++) out[b * 128 + t] = acc[b] * invN + bb;
}

// ---------------- launcher ----------------

extern "C" void kernel_launch(void* const* d_in, const int* in_sizes, int n_in,
                              void* d_out, int out_size, void* d_ws, size_t ws_size,
                              hipStream_t stream) {
    const float* gene = (const float*)d_in[0];
    const float* W1   = (const float*)d_in[1];
    const float* b1   = (const float*)d_in[2];
    const float* W2   = (const float*)d_in[3];
    const float* b2   = (const float*)d_in[4];
    const int*   gid  = (const int*)d_in[5];
    const int*   eidx = (const int*)d_in[6];
    int N = in_sizes[5];
    int E = in_sizes[6] / 2;
    const int* src = eidx;
    const int* dst = eidx + E;
    float* out = (float*)d_out;

    char* p = (char*)d_ws;
    auto alloc = [&](size_t bytes) -> char* {
        char* r = p; p += (bytes + 255) & ~(size_t)255; return r;
    };
    size_t csr_cap = (size_t)E + 8 * (size_t)N;          // padded upper bound (entries)
    int*   ideg   = (int*)  alloc((size_t)N * 4);
    float* dinv   = (float*)alloc((size_t)N * 4);
    float* cval   = (float*)alloc((size_t)N * 4);
    int*   padcnt = (int*)  alloc((size_t)N * 4);
    int*   offs   = (int*)  alloc((size_t)N * 4);
    int*   epos   = (int*)  alloc((size_t)E * 4);        // per-edge slot within its dst segment
    int*   ticket = (int*)  alloc(256);
    int2*  csr    = (int2*) alloc(csr_cap * 8);
    float* s_acc  = (float*)alloc(8 * 1024 * 4);
    uint*  h2     = (uint*) alloc((size_t)NG * BB * FD * 2);   // 41 MB, bf16 [pair][g][f][2]
    ushort* w1t   = (ushort*)alloc(128 * 128 * 2);             // bf16 W1^T [j][k]

    int nb = (N + 255) / 256;   // 196
    int eb = (E + 255) / 256;   // 3125
    int hblk = 4 * (NG / 32);   // 2500 h-tiles total: HA + HB + HC

    const int NBLK = 2048;      // 512 blocks/pair * 8 waves = 4096 waves per pair
    int wpp = (NBLK / 4) * 8;   // waves per pair

    k_setup <<<nb, 256, 0, stream>>>(ideg, s_acc, ticket, W1, w1t, N);
    k_counth<<<eb + HA, 256, 0, stream>>>(dst, ideg, epos, E, eb, gene, w1t, h2);
    k_scanh <<<nb + HB, 256, 0, stream>>>(ideg, dinv, cval, padcnt, offs, gid,
                                          csr, ticket, N, nb, gene, w1t, h2);
    k_fillh <<<eb + (hblk - HA - HB), 256, 0, stream>>>(src, dst, gid, dinv, cval, offs,
                                                        epos, csr, E, eb, gene, w1t, h2);
    k_aggp  <<<NBLK, 512, 0, stream>>>(h2, csr, offs, padcnt,
                                       cval, b1, s_acc, N, wpp);
    k_final <<<1, 128, 0, stream>>>(s_acc, W2, b2, out, 1.0f / (float)N);
}